// Round 1
// baseline (3358.574 us; speedup 1.0000x reference)
//
#include <hip/hip_runtime.h>
#include <hip/hip_bf16.h>
#include <cfloat>

// Problem constants
#define BB 8
#define NN 2048
#define KK 20
#define EPSV 1e-5f

// ---------------------------------------------------------------------------
// pack x (B,3,N) -> F0 (B,N,3) and xx (B,N)
__global__ __launch_bounds__(256) void pack_x(const float* __restrict__ x,
                                              float* __restrict__ F0,
                                              float* __restrict__ xx) {
  int b = blockIdx.y;
  int n = blockIdx.x * 256 + threadIdx.x;
  if (n >= NN) return;
  float a = x[((size_t)b * 3 + 0) * NN + n];
  float c = x[((size_t)b * 3 + 1) * NN + n];
  float d = x[((size_t)b * 3 + 2) * NN + n];
  size_t r = (size_t)b * NN + n;
  F0[r * 3 + 0] = a;
  F0[r * 3 + 1] = c;
  F0[r * 3 + 2] = d;
  xx[r] = a * a + c * c + d * d;
}

// ---------------------------------------------------------------------------
// norms over C channels of F (pre-offset pointer), ld = ldf
__global__ __launch_bounds__(256) void norms_k(const float* __restrict__ F, int ldf, int C,
                                               float* __restrict__ xx) {
  int b = blockIdx.y;
  int n = blockIdx.x * 256 + threadIdx.x;
  if (n >= NN) return;
  const float* f = F + ((size_t)b * NN + n) * ldf;
  float s = 0.f;
  if ((C & 3) == 0) {
    for (int c = 0; c < C; c += 4) {
      float4 v = *(const float4*)(f + c);
      s += v.x * v.x + v.y * v.y + v.z * v.z + v.w * v.w;
    }
  } else {
    for (int c = 0; c < C; ++c) { float v = f[c]; s += v * v; }
  }
  xx[(size_t)b * NN + n] = s;
}

// ---------------------------------------------------------------------------
// kNN: 8 rows per block. dist rows in LDS (64KB), then 20x stable wave argmax.
__global__ __launch_bounds__(256) void knn_kernel(const float* __restrict__ F, int ldf, int C,
                                                  const float* __restrict__ xx,
                                                  int* __restrict__ idx) {
  __shared__ float sd[8][NN];
  int b = blockIdx.y;
  int r0 = blockIdx.x * 8;
  int tid = threadIdx.x;
  const float* Fb = F + (size_t)b * NN * ldf;
  const float* xxb = xx + (size_t)b * NN;

  // phase 1: distances for 8 rows x all m
  for (int i = 0; i < NN; i += 256) {
    int m = i + tid;
    float acc[8];
#pragma unroll
    for (int r = 0; r < 8; ++r) acc[r] = 0.f;
    const float* fm = Fb + (size_t)m * ldf;
    if ((C & 3) == 0) {
      for (int c = 0; c < C; c += 4) {
        float4 fv = *(const float4*)(fm + c);
#pragma unroll
        for (int r = 0; r < 8; ++r) {
          const float* fr = Fb + (size_t)(r0 + r) * ldf + c;
          acc[r] += fv.x * fr[0] + fv.y * fr[1] + fv.z * fr[2] + fv.w * fr[3];
        }
      }
    } else {
      for (int c = 0; c < C; ++c) {
        float fv = fm[c];
#pragma unroll
        for (int r = 0; r < 8; ++r) acc[r] += fv * Fb[(size_t)(r0 + r) * ldf + c];
      }
    }
    float xm = xxb[m];
#pragma unroll
    for (int r = 0; r < 8; ++r) {
      float d = 2.f * acc[r] - xxb[r0 + r];  // 2a exact; matches ref op order
      d = d - xm;
      sd[r][m] = d;
    }
  }
  __syncthreads();

  // phase 2: per-wave top-20 (stable: ties -> min index), waves own rows {w, w+4}
  int wave = tid >> 6, lane = tid & 63;
  for (int s = 0; s < 2; ++s) {
    int r = wave + 4 * s;
    volatile float* row = &sd[r][0];
    int rowi = r0 + r;
    for (int it = 0; it < KK; ++it) {
      float bv = -FLT_MAX;
      int bi = 0x7fffffff;
      for (int j = lane; j < NN; j += 64) {
        float v = row[j];
        if (v > bv || (v == bv && j < bi)) { bv = v; bi = j; }
      }
#pragma unroll
      for (int off = 32; off > 0; off >>= 1) {
        float ov = __shfl_xor(bv, off);
        int oi = __shfl_xor(bi, off);
        if (ov > bv || (ov == bv && oi < bi)) { bv = ov; bi = oi; }
      }
      if (lane == 0) {
        idx[((size_t)b * NN + rowi) * KK + it] = bi;
        row[bi] = -FLT_MAX;
      }
    }
  }
}

// ---------------------------------------------------------------------------
// prep: split w (O,2C) -> Wa (O,C), Wd = Wb - Wa; sv = g/sqrt(v+eps);
//       tq = (bias - m)*sv + be.  (C==0 -> only sv/tq, for the final layer)
__global__ __launch_bounds__(256) void prep_edge(const float* __restrict__ w,
                                                 const float* __restrict__ bias,
                                                 const float* __restrict__ g,
                                                 const float* __restrict__ be,
                                                 const float* __restrict__ m,
                                                 const float* __restrict__ v,
                                                 float* __restrict__ Wa, float* __restrict__ Wd,
                                                 float* __restrict__ sv, float* __restrict__ tq,
                                                 int O, int C) {
  int i = blockIdx.x * 256 + threadIdx.x;
  if (i < O * C) {
    int o = i / C, c = i % C;
    float wa = w[(size_t)o * 2 * C + c];
    float wb = w[(size_t)o * 2 * C + C + c];
    Wa[i] = wa;
    Wd[i] = wb - wa;
  }
  if (i < O) {
    float s = g[i] / sqrtf(v[i] + EPSV);
    sv[i] = s;
    tq[i] = (bias[i] - m[i]) * s + be[i];
  }
}

// ---------------------------------------------------------------------------
// tiled dual GEMM: P[b][n][o] = (sum_c F[n][c]*Wa[o][c])*sv[o] + (tp?tp[o]:0)
//                  Q[b][n][o] = (sum_c F[n][c]*Wd[o][c])*sv[o] + tq[o]   (DUAL)
template <bool DUAL>
__global__ __launch_bounds__(256) void gemm_pq(const float* __restrict__ F, int ldf, int C,
                                               const float* __restrict__ Wa,
                                               const float* __restrict__ Wd,
                                               const float* __restrict__ sv,
                                               const float* __restrict__ tp,
                                               const float* __restrict__ tq,
                                               float* __restrict__ P, float* __restrict__ Q,
                                               int O) {
  __shared__ __align__(16) float Fs[8][64];
  __shared__ __align__(16) float Was[8][64];
  __shared__ __align__(16) float Wds[8][64];
  int b = blockIdx.z;
  int n0 = blockIdx.x * 64, o0 = blockIdx.y * 64;
  int tid = threadIdx.x;
  int tn = tid & 15, to = tid >> 4;
  float accP[4][4] = {{0.f}};
  float accQ[4][4] = {{0.f}};
  const float* Fb = F + (size_t)b * NN * ldf;

  for (int c0 = 0; c0 < C; c0 += 8) {
    for (int e = tid; e < 512; e += 256) {
      int n = e >> 3, k = e & 7, c = c0 + k;
      Fs[k][n] = (c < C) ? Fb[(size_t)(n0 + n) * ldf + c] : 0.f;
      Was[k][n] = (c < C) ? Wa[(size_t)(o0 + n) * C + c] : 0.f;
      if (DUAL) Wds[k][n] = (c < C) ? Wd[(size_t)(o0 + n) * C + c] : 0.f;
    }
    __syncthreads();
#pragma unroll
    for (int k = 0; k < 8; ++k) {
      float4 fq = *(const float4*)&Fs[k][tn * 4];
      float4 aq = *(const float4*)&Was[k][to * 4];
      float fa[4] = {fq.x, fq.y, fq.z, fq.w};
      float aa[4] = {aq.x, aq.y, aq.z, aq.w};
#pragma unroll
      for (int i = 0; i < 4; ++i)
#pragma unroll
        for (int j = 0; j < 4; ++j) accP[i][j] += fa[i] * aa[j];
      if (DUAL) {
        float4 dq = *(const float4*)&Wds[k][to * 4];
        float da[4] = {dq.x, dq.y, dq.z, dq.w};
#pragma unroll
        for (int i = 0; i < 4; ++i)
#pragma unroll
          for (int j = 0; j < 4; ++j) accQ[i][j] += fa[i] * da[j];
      }
    }
    __syncthreads();
  }

#pragma unroll
  for (int j = 0; j < 4; ++j) {
    int o = o0 + to * 4 + j;
    float s = sv[o];
    float tpv = (tp != nullptr) ? tp[o] : 0.f;
    float tqv = DUAL ? tq[o] : 0.f;
#pragma unroll
    for (int i = 0; i < 4; ++i) {
      int n = n0 + tn * 4 + i;
      size_t base = ((size_t)b * NN + n) * O + o;
      P[base] = accP[i][j] * s + tpv;
      if (DUAL) Q[base] = accQ[i][j] * s + tqv;
    }
  }
}

// ---------------------------------------------------------------------------
// gather-max: out H[b][n][c0+o] = max(0, max_k (P[b][idx[n][k]][o] + Q[b][n][o]))
__global__ __launch_bounds__(256) void gather_max(const float* __restrict__ P,
                                                  const float* __restrict__ Q,
                                                  const int* __restrict__ idx,
                                                  float* __restrict__ H, int c0, int O) {
  int b = blockIdx.y;
  int n = blockIdx.x;
  int o = threadIdx.x;
  const int* id = idx + ((size_t)b * NN + n) * KK;
  float q = Q[((size_t)b * NN + n) * O + o];
  float best = -FLT_MAX;
#pragma unroll 4
  for (int k = 0; k < KK; ++k) {
    int j = id[k];
    float v = P[((size_t)b * NN + j) * O + o] + q;
    best = fmaxf(best, v);
  }
  best = fmaxf(best, 0.f);  // relu (before max == after max)
  H[((size_t)b * NN + n) * 448 + c0 + o] = best;
}

// ---------------------------------------------------------------------------
// final reduce: out[b][o] = max(0, max_n Z[b][n][o])
__global__ __launch_bounds__(256) void reduce_max(const float* __restrict__ Z,
                                                  float* __restrict__ out) {
  int b = blockIdx.y;
  int o = blockIdx.x * 256 + threadIdx.x;  // o < 512
  float m = -FLT_MAX;
  for (int n = 0; n < NN; ++n) {
    float v = Z[((size_t)b * NN + n) * 512 + o];
    m = fmaxf(m, v);
  }
  out[(size_t)b * 512 + o] = fmaxf(m, 0.f);
}

// ---------------------------------------------------------------------------
extern "C" void kernel_launch(void* const* d_in, const int* in_sizes, int n_in,
                              void* d_out, int out_size, void* d_ws, size_t ws_size,
                              hipStream_t stream) {
  const float* x = (const float*)d_in[0];
  const float* w1 = (const float*)d_in[1];
  const float* b1 = (const float*)d_in[2];
  const float* g1 = (const float*)d_in[3];
  const float* be1 = (const float*)d_in[4];
  const float* m1 = (const float*)d_in[5];
  const float* v1 = (const float*)d_in[6];
  const float* w2 = (const float*)d_in[7];
  const float* b2 = (const float*)d_in[8];
  const float* g2 = (const float*)d_in[9];
  const float* be2 = (const float*)d_in[10];
  const float* m2 = (const float*)d_in[11];
  const float* v2 = (const float*)d_in[12];
  const float* w3 = (const float*)d_in[13];
  const float* b3 = (const float*)d_in[14];
  const float* g3 = (const float*)d_in[15];
  const float* be3 = (const float*)d_in[16];
  const float* m3 = (const float*)d_in[17];
  const float* v3 = (const float*)d_in[18];
  const float* wo = (const float*)d_in[19];
  const float* bo = (const float*)d_in[20];
  const float* go = (const float*)d_in[21];
  const float* beo = (const float*)d_in[22];
  const float* mo = (const float*)d_in[23];
  const float* vo = (const float*)d_in[24];

  char* ws = (char*)d_ws;
  float* H = (float*)(ws + 0);              // 8*2048*448*4 = 29360128
  float* F0 = (float*)(ws + 29360128);      // 196608
  float* xx = (float*)(ws + 29556736);      // 65536
  int* idx = (int*)(ws + 29622272);         // 1310720
  float* P = (float*)(ws + 30932992);       // 16777216
  float* Q = (float*)(ws + 47710208);       // 16777216 (P..Q+ = 33.5MB, reused as Z)
  float* Wa = (float*)(ws + 64487424);      // 131072
  float* Wd = (float*)(ws + 64618496);      // 131072
  float* sv = (float*)(ws + 64749568);      // 4096
  float* tq = (float*)(ws + 64753664);      // 4096
  float* Z = P;

  dim3 blk(256);

  pack_x<<<dim3(8, BB), blk, 0, stream>>>(x, F0, xx);

  // ---- layer 1: C=3, O=64
  prep_edge<<<dim3(1), blk, 0, stream>>>(w1, b1, g1, be1, m1, v1, Wa, Wd, sv, tq, 64, 3);
  knn_kernel<<<dim3(NN / 8, BB), blk, 0, stream>>>(F0, 3, 3, xx, idx);
  gemm_pq<true><<<dim3(32, 1, BB), blk, 0, stream>>>(F0, 3, 3, Wa, Wd, sv, nullptr, tq, P, Q, 64);
  gather_max<<<dim3(NN, BB), dim3(64), 0, stream>>>(P, Q, idx, H, 0, 64);
  norms_k<<<dim3(8, BB), blk, 0, stream>>>(H, 448, 64, xx);

  // ---- layer 2: C=64, O=128
  prep_edge<<<dim3(32), blk, 0, stream>>>(w2, b2, g2, be2, m2, v2, Wa, Wd, sv, tq, 128, 64);
  knn_kernel<<<dim3(NN / 8, BB), blk, 0, stream>>>(H, 448, 64, xx, idx);
  gemm_pq<true><<<dim3(32, 2, BB), blk, 0, stream>>>(H, 448, 64, Wa, Wd, sv, nullptr, tq, P, Q, 128);
  gather_max<<<dim3(NN, BB), dim3(128), 0, stream>>>(P, Q, idx, H, 64, 128);
  norms_k<<<dim3(8, BB), blk, 0, stream>>>(H + 64, 448, 128, xx);

  // ---- layer 3: C=128, O=256
  prep_edge<<<dim3(128), blk, 0, stream>>>(w3, b3, g3, be3, m3, v3, Wa, Wd, sv, tq, 256, 128);
  knn_kernel<<<dim3(NN / 8, BB), blk, 0, stream>>>(H + 64, 448, 128, xx, idx);
  gemm_pq<true><<<dim3(32, 4, BB), blk, 0, stream>>>(H + 64, 448, 128, Wa, Wd, sv, nullptr, tq, P, Q, 256);
  gather_max<<<dim3(NN, BB), dim3(256), 0, stream>>>(P, Q, idx, H, 192, 256);

  // ---- final linear: C=448, O=512 (BN folded via sv/tq-as-tp)
  prep_edge<<<dim3(2), blk, 0, stream>>>(nullptr, bo, go, beo, mo, vo, nullptr, nullptr, sv, tq, 512, 0);
  gemm_pq<false><<<dim3(32, 8, BB), blk, 0, stream>>>(H, 448, 448, wo, nullptr, sv, tq, nullptr, Z, nullptr, 512);
  reduce_max<<<dim3(2, BB), blk, 0, stream>>>(Z, (float*)d_out);
}

// Round 2
// 1396.436 us; speedup vs baseline: 2.4051x; 2.4051x over previous
//
#include <hip/hip_runtime.h>
#include <hip/hip_bf16.h>
#include <cfloat>

// Problem constants
#define BB 8
#define NN 2048
#define KK 20
#define EPSV 1e-5f

// ---------------------------------------------------------------------------
// pack x (B,3,N) -> F0 (B,N,3) and xx (B,N)
__global__ __launch_bounds__(256) void pack_x(const float* __restrict__ x,
                                              float* __restrict__ F0,
                                              float* __restrict__ xx) {
  int b = blockIdx.y;
  int n = blockIdx.x * 256 + threadIdx.x;
  if (n >= NN) return;
  float a = x[((size_t)b * 3 + 0) * NN + n];
  float c = x[((size_t)b * 3 + 1) * NN + n];
  float d = x[((size_t)b * 3 + 2) * NN + n];
  size_t r = (size_t)b * NN + n;
  F0[r * 3 + 0] = a;
  F0[r * 3 + 1] = c;
  F0[r * 3 + 2] = d;
  xx[r] = a * a + c * c + d * d;
}

// ---------------------------------------------------------------------------
// norms over C channels of F (pre-offset pointer), ld = ldf
__global__ __launch_bounds__(256) void norms_k(const float* __restrict__ F, int ldf, int C,
                                               float* __restrict__ xx) {
  int b = blockIdx.y;
  int n = blockIdx.x * 256 + threadIdx.x;
  if (n >= NN) return;
  const float* f = F + ((size_t)b * NN + n) * ldf;
  float s = 0.f;
  if ((C & 3) == 0) {
    for (int c = 0; c < C; c += 4) {
      float4 v = *(const float4*)(f + c);
      s += v.x * v.x + v.y * v.y + v.z * v.z + v.w * v.w;
    }
  } else {
    for (int c = 0; c < C; ++c) { float v = f[c]; s += v * v; }
  }
  xx[(size_t)b * NN + n] = s;
}

// ---------------------------------------------------------------------------
// kNN v2: 4 rows/block (one per wave). Phase 1: all 256 threads compute
// distances into sd[4][2048] (32KB LDS -> 4 blocks/CU). Phase 2: each wave
// pulls its row into 32 registers/lane and does 20x incremental wave-argmax
// (winner-only masked rescan; no LDS traffic, no volatile).
template <int C>
__global__ __launch_bounds__(256) void knn2(const float* __restrict__ F, int ldf,
                                            const float* __restrict__ xx,
                                            int* __restrict__ idx) {
  __shared__ float sd[4][NN];
  __shared__ __align__(16) float rowf[4][(C < 4) ? 4 : C];
  __shared__ float rn[4];
  int b = blockIdx.y;
  int r0 = blockIdx.x * 4;
  int tid = threadIdx.x;
  const float* Fb = F + (size_t)b * NN * ldf;
  const float* xxb = xx + (size_t)b * NN;

  for (int e = tid; e < 4 * C; e += 256) {
    int r = e / C, c = e % C;
    rowf[r][c] = Fb[(size_t)(r0 + r) * ldf + c];
  }
  if (tid < 4) rn[tid] = xxb[r0 + tid];
  __syncthreads();

  // phase 1: distances for 4 rows x all m
#pragma unroll
  for (int chunk = 0; chunk < 8; ++chunk) {
    int m = chunk * 256 + tid;
    const float* fm = Fb + (size_t)m * ldf;
    float acc[4] = {0.f, 0.f, 0.f, 0.f};
    if constexpr ((C & 3) == 0) {
#pragma unroll 8
      for (int c = 0; c < C; c += 4) {
        float4 fv = *(const float4*)(fm + c);
#pragma unroll
        for (int r = 0; r < 4; ++r) {
          float4 rv = *(const float4*)&rowf[r][c];
          acc[r] += fv.x * rv.x + fv.y * rv.y + fv.z * rv.z + fv.w * rv.w;
        }
      }
    } else {
      for (int c = 0; c < C; ++c) {
        float fv = fm[c];
#pragma unroll
        for (int r = 0; r < 4; ++r) acc[r] += fv * rowf[r][c];
      }
    }
    float xm = xxb[m];
#pragma unroll
    for (int r = 0; r < 4; ++r) sd[r][m] = (2.f * acc[r] - rn[r]) - xm;
  }
  __syncthreads();

  // phase 2: wave w owns row r0+w; distances live in registers
  int wv = tid >> 6, lane = tid & 63;
  float f[32];
#pragma unroll
  for (int i = 0; i < 32; ++i) f[i] = sd[wv][i * 64 + lane];

  float lv = -FLT_MAX;
  int lm = 0x7fffffff;
#pragma unroll
  for (int i = 0; i < 32; ++i) {
    if (f[i] > lv) { lv = f[i]; lm = i * 64 + lane; }  // ascending i -> min m on ties
  }

  unsigned used = 0u;
  int myidx = 0;
  for (int it = 0; it < KK; ++it) {
    float bv = lv;
    int bm = lm;
#pragma unroll
    for (int off = 32; off > 0; off >>= 1) {
      float ov = __shfl_xor(bv, off);
      int om = __shfl_xor(bm, off);
      if (ov > bv || (ov == bv && om < bm)) { bv = ov; bm = om; }
    }
    if (lane == it) myidx = bm;
    if (lm == bm) {  // exactly the winning lane
      used |= 1u << (lm >> 6);
      lv = -FLT_MAX;
      lm = 0x7fffffff;
#pragma unroll
      for (int i = 0; i < 32; ++i) {
        float v = (used & (1u << i)) ? -FLT_MAX : f[i];
        if (v > lv) { lv = v; lm = i * 64 + lane; }
      }
    }
  }
  if (lane < KK) idx[((size_t)b * NN + r0 + wv) * KK + lane] = myidx;
}

// ---------------------------------------------------------------------------
// prep: split w (O,2C) -> Wa (O,C), Wd = Wb - Wa; sv = g/sqrt(v+eps);
//       tq = (bias - m)*sv + be.  (C==0 -> only sv/tq, for the final layer)
__global__ __launch_bounds__(256) void prep_edge(const float* __restrict__ w,
                                                 const float* __restrict__ bias,
                                                 const float* __restrict__ g,
                                                 const float* __restrict__ be,
                                                 const float* __restrict__ m,
                                                 const float* __restrict__ v,
                                                 float* __restrict__ Wa, float* __restrict__ Wd,
                                                 float* __restrict__ sv, float* __restrict__ tq,
                                                 int O, int C) {
  int i = blockIdx.x * 256 + threadIdx.x;
  if (i < O * C) {
    int o = i / C, c = i % C;
    float wa = w[(size_t)o * 2 * C + c];
    float wb = w[(size_t)o * 2 * C + C + c];
    Wa[i] = wa;
    Wd[i] = wb - wa;
  }
  if (i < O) {
    float s = g[i] / sqrtf(v[i] + EPSV);
    sv[i] = s;
    tq[i] = (bias[i] - m[i]) * s + be[i];
  }
}

// ---------------------------------------------------------------------------
// tiled dual GEMM: P[b][n][o] = (sum_c F[n][c]*Wa[o][c])*sv[o] + (tp?tp[o]:0)
//                  Q[b][n][o] = (sum_c F[n][c]*Wd[o][c])*sv[o] + tq[o]   (DUAL)
template <bool DUAL>
__global__ __launch_bounds__(256) void gemm_pq(const float* __restrict__ F, int ldf, int C,
                                               const float* __restrict__ Wa,
                                               const float* __restrict__ Wd,
                                               const float* __restrict__ sv,
                                               const float* __restrict__ tp,
                                               const float* __restrict__ tq,
                                               float* __restrict__ P, float* __restrict__ Q,
                                               int O) {
  __shared__ __align__(16) float Fs[8][64];
  __shared__ __align__(16) float Was[8][64];
  __shared__ __align__(16) float Wds[8][64];
  int b = blockIdx.z;
  int n0 = blockIdx.x * 64, o0 = blockIdx.y * 64;
  int tid = threadIdx.x;
  int tn = tid & 15, to = tid >> 4;
  float accP[4][4] = {{0.f}};
  float accQ[4][4] = {{0.f}};
  const float* Fb = F + (size_t)b * NN * ldf;

  for (int c0 = 0; c0 < C; c0 += 8) {
    for (int e = tid; e < 512; e += 256) {
      int n = e >> 3, k = e & 7, c = c0 + k;
      Fs[k][n] = (c < C) ? Fb[(size_t)(n0 + n) * ldf + c] : 0.f;
      Was[k][n] = (c < C) ? Wa[(size_t)(o0 + n) * C + c] : 0.f;
      if (DUAL) Wds[k][n] = (c < C) ? Wd[(size_t)(o0 + n) * C + c] : 0.f;
    }
    __syncthreads();
#pragma unroll
    for (int k = 0; k < 8; ++k) {
      float4 fq = *(const float4*)&Fs[k][tn * 4];
      float4 aq = *(const float4*)&Was[k][to * 4];
      float fa[4] = {fq.x, fq.y, fq.z, fq.w};
      float aa[4] = {aq.x, aq.y, aq.z, aq.w};
#pragma unroll
      for (int i = 0; i < 4; ++i)
#pragma unroll
        for (int j = 0; j < 4; ++j) accP[i][j] += fa[i] * aa[j];
      if (DUAL) {
        float4 dq = *(const float4*)&Wds[k][to * 4];
        float da[4] = {dq.x, dq.y, dq.z, dq.w};
#pragma unroll
        for (int i = 0; i < 4; ++i)
#pragma unroll
          for (int j = 0; j < 4; ++j) accQ[i][j] += fa[i] * da[j];
      }
    }
    __syncthreads();
  }

#pragma unroll
  for (int j = 0; j < 4; ++j) {
    int o = o0 + to * 4 + j;
    float s = sv[o];
    float tpv = (tp != nullptr) ? tp[o] : 0.f;
    float tqv = DUAL ? tq[o] : 0.f;
#pragma unroll
    for (int i = 0; i < 4; ++i) {
      int n = n0 + tn * 4 + i;
      size_t base = ((size_t)b * NN + n) * O + o;
      P[base] = accP[i][j] * s + tpv;
      if (DUAL) Q[base] = accQ[i][j] * s + tqv;
    }
  }
}

// ---------------------------------------------------------------------------
// gather-max: out H[b][n][c0+o] = max(0, max_k (P[b][idx[n][k]][o] + Q[b][n][o]))
__global__ void gather_max(const float* __restrict__ P,
                           const float* __restrict__ Q,
                           const int* __restrict__ idx,
                           float* __restrict__ H, int c0, int O) {
  int b = blockIdx.y;
  int n = blockIdx.x;
  int o = threadIdx.x;
  const int* id = idx + ((size_t)b * NN + n) * KK;
  float q = Q[((size_t)b * NN + n) * O + o];
  float best = -FLT_MAX;
#pragma unroll 4
  for (int k = 0; k < KK; ++k) {
    int j = id[k];
    float v = P[((size_t)b * NN + j) * O + o] + q;
    best = fmaxf(best, v);
  }
  best = fmaxf(best, 0.f);  // relu (before max == after max)
  H[((size_t)b * NN + n) * 448 + c0 + o] = best;
}

// ---------------------------------------------------------------------------
// final reduce: out[b][o] = max over n-chunk, via uint atomicMax (values >= 0)
__global__ __launch_bounds__(256) void reduce_max_part(const float* __restrict__ Z,
                                                       unsigned* __restrict__ out) {
  int b = blockIdx.y;
  int o = blockIdx.x * 256 + threadIdx.x;  // o < 512
  int n0 = blockIdx.z * 256;
  float m = 0.f;  // relu floor
  for (int n = n0; n < n0 + 256; ++n) {
    float v = Z[((size_t)b * NN + n) * 512 + o];
    m = fmaxf(m, v);
  }
  // post-relu floats are >= 0 -> uint bit pattern is order-preserving
  atomicMax(&out[(size_t)b * 512 + o], __float_as_uint(m));
}

// ---------------------------------------------------------------------------
extern "C" void kernel_launch(void* const* d_in, const int* in_sizes, int n_in,
                              void* d_out, int out_size, void* d_ws, size_t ws_size,
                              hipStream_t stream) {
  const float* x = (const float*)d_in[0];
  const float* w1 = (const float*)d_in[1];
  const float* b1 = (const float*)d_in[2];
  const float* g1 = (const float*)d_in[3];
  const float* be1 = (const float*)d_in[4];
  const float* m1 = (const float*)d_in[5];
  const float* v1 = (const float*)d_in[6];
  const float* w2 = (const float*)d_in[7];
  const float* b2 = (const float*)d_in[8];
  const float* g2 = (const float*)d_in[9];
  const float* be2 = (const float*)d_in[10];
  const float* m2 = (const float*)d_in[11];
  const float* v2 = (const float*)d_in[12];
  const float* w3 = (const float*)d_in[13];
  const float* b3 = (const float*)d_in[14];
  const float* g3 = (const float*)d_in[15];
  const float* be3 = (const float*)d_in[16];
  const float* m3 = (const float*)d_in[17];
  const float* v3 = (const float*)d_in[18];
  const float* wo = (const float*)d_in[19];
  const float* bo = (const float*)d_in[20];
  const float* go = (const float*)d_in[21];
  const float* beo = (const float*)d_in[22];
  const float* mo = (const float*)d_in[23];
  const float* vo = (const float*)d_in[24];

  char* ws = (char*)d_ws;
  float* H = (float*)(ws + 0);              // 8*2048*448*4 = 29360128
  float* F0 = (float*)(ws + 29360128);      // 196608
  float* xx = (float*)(ws + 29556736);      // 65536
  int* idx = (int*)(ws + 29622272);         // 1310720
  float* P = (float*)(ws + 30932992);       // 16777216
  float* Q = (float*)(ws + 47710208);       // 16777216 (P..Q+ = 33.5MB, reused as Z)
  float* Wa = (float*)(ws + 64487424);      // 131072
  float* Wd = (float*)(ws + 64618496);      // 131072
  float* sv = (float*)(ws + 64749568);      // 4096
  float* tq = (float*)(ws + 64753664);      // 4096
  float* Z = P;

  dim3 blk(256);

  pack_x<<<dim3(8, BB), blk, 0, stream>>>(x, F0, xx);

  // ---- layer 1: C=3, O=64
  prep_edge<<<dim3(1), blk, 0, stream>>>(w1, b1, g1, be1, m1, v1, Wa, Wd, sv, tq, 64, 3);
  knn2<3><<<dim3(NN / 4, BB), blk, 0, stream>>>(F0, 3, xx, idx);
  gemm_pq<true><<<dim3(32, 1, BB), blk, 0, stream>>>(F0, 3, 3, Wa, Wd, sv, nullptr, tq, P, Q, 64);
  gather_max<<<dim3(NN, BB), dim3(64), 0, stream>>>(P, Q, idx, H, 0, 64);
  norms_k<<<dim3(8, BB), blk, 0, stream>>>(H, 448, 64, xx);

  // ---- layer 2: C=64, O=128
  prep_edge<<<dim3(32), blk, 0, stream>>>(w2, b2, g2, be2, m2, v2, Wa, Wd, sv, tq, 128, 64);
  knn2<64><<<dim3(NN / 4, BB), blk, 0, stream>>>(H, 448, xx, idx);
  gemm_pq<true><<<dim3(32, 2, BB), blk, 0, stream>>>(H, 448, 64, Wa, Wd, sv, nullptr, tq, P, Q, 128);
  gather_max<<<dim3(NN, BB), dim3(128), 0, stream>>>(P, Q, idx, H, 64, 128);
  norms_k<<<dim3(8, BB), blk, 0, stream>>>(H + 64, 448, 128, xx);

  // ---- layer 3: C=128, O=256
  prep_edge<<<dim3(128), blk, 0, stream>>>(w3, b3, g3, be3, m3, v3, Wa, Wd, sv, tq, 256, 128);
  knn2<128><<<dim3(NN / 4, BB), blk, 0, stream>>>(H + 64, 448, xx, idx);
  gemm_pq<true><<<dim3(32, 4, BB), blk, 0, stream>>>(H + 64, 448, 128, Wa, Wd, sv, nullptr, tq, P, Q, 256);
  gather_max<<<dim3(NN, BB), dim3(256), 0, stream>>>(P, Q, idx, H, 192, 256);

  // ---- final linear: C=448, O=512 (BN folded via sv/tq-as-tp)
  prep_edge<<<dim3(2), blk, 0, stream>>>(nullptr, bo, go, beo, mo, vo, nullptr, nullptr, sv, tq, 512, 0);
  gemm_pq<false><<<dim3(32, 8, BB), blk, 0, stream>>>(H, 448, 448, wo, nullptr, sv, tq, nullptr, Z, nullptr, 512);

  hipMemsetAsync(d_out, 0, (size_t)out_size * sizeof(float), stream);
  reduce_max_part<<<dim3(2, BB, 8), blk, 0, stream>>>(Z, (unsigned*)d_out);
}

// Round 3
// 986.892 us; speedup vs baseline: 3.4032x; 1.4150x over previous
//
#include <hip/hip_runtime.h>
#include <hip/hip_bf16.h>
#include <cfloat>

// Problem constants
#define BB 8
#define NN 2048
#define KK 20
#define EPSV 1e-5f

// ---------------------------------------------------------------------------
// pack x (B,3,N) -> F0 (B,N,3) and xx (B,N)
__global__ __launch_bounds__(256) void pack_x(const float* __restrict__ x,
                                              float* __restrict__ F0,
                                              float* __restrict__ xx) {
  int b = blockIdx.y;
  int n = blockIdx.x * 256 + threadIdx.x;
  if (n >= NN) return;
  float a = x[((size_t)b * 3 + 0) * NN + n];
  float c = x[((size_t)b * 3 + 1) * NN + n];
  float d = x[((size_t)b * 3 + 2) * NN + n];
  size_t r = (size_t)b * NN + n;
  F0[r * 3 + 0] = a;
  F0[r * 3 + 1] = c;
  F0[r * 3 + 2] = d;
  xx[r] = a * a + c * c + d * d;
}

// ---------------------------------------------------------------------------
// norms over C channels of F (pre-offset pointer), ld = ldf
__global__ __launch_bounds__(256) void norms_k(const float* __restrict__ F, int ldf, int C,
                                               float* __restrict__ xx) {
  int b = blockIdx.y;
  int n = blockIdx.x * 256 + threadIdx.x;
  if (n >= NN) return;
  const float* f = F + ((size_t)b * NN + n) * ldf;
  float s = 0.f;
  for (int c = 0; c < C; c += 4) {
    float4 v = *(const float4*)(f + c);
    s += v.x * v.x + v.y * v.y + v.z * v.z + v.w * v.w;
  }
  xx[(size_t)b * NN + n] = s;
}

// ---------------------------------------------------------------------------
// 32x32 tiled transpose: src [b][n][C] (ld lds_) -> dst [b][c][n] (ld NN)
__global__ __launch_bounds__(256) void transpose_k(const float* __restrict__ src, int lds_, int C,
                                                   float* __restrict__ dst) {
  __shared__ float t[32][33];
  int b = blockIdx.z;
  int n0 = blockIdx.x * 32, c0 = blockIdx.y * 32;
  int tx = threadIdx.x & 31, ty = threadIdx.x >> 5;  // 32 x 8
#pragma unroll
  for (int i = 0; i < 32; i += 8) {
    t[ty + i][tx] = src[((size_t)b * NN + n0 + ty + i) * lds_ + c0 + tx];
  }
  __syncthreads();
#pragma unroll
  for (int i = 0; i < 32; i += 8) {
    dst[((size_t)b * C + c0 + ty + i) * NN + n0 + tx] = t[tx][ty + i];
  }
}

// ---------------------------------------------------------------------------
// kNN v3: 4 rows/block (one per wave). Phase 1: coalesced m-side loads from
// transposed features FT[c][n]; each lane owns 4 consecutive m. Phase 2: each
// wave pulls its row into 32 registers/lane, 20x incremental wave-argmax.
template <int C>
__global__ __launch_bounds__(256) void knn3(const float* __restrict__ FT, int ldft,
                                            const float* __restrict__ F, int ldf,
                                            const float* __restrict__ xx,
                                            int* __restrict__ idx) {
  __shared__ float sd[4][NN];
  __shared__ __align__(16) float rowf[4][(C < 4) ? 4 : C];
  int b = blockIdx.y;
  int r0 = blockIdx.x * 4;
  int tid = threadIdx.x;
  const float* FTb = FT + (size_t)b * C * ldft;
  const float* Fb = F + (size_t)b * NN * ldf;
  const float* xxb = xx + (size_t)b * NN;

  for (int e = tid; e < 4 * C; e += 256) {
    int r = e / C, c = e % C;
    rowf[r][c] = Fb[(size_t)(r0 + r) * ldf + c];
  }
  __syncthreads();

  float rnr[4];
#pragma unroll
  for (int r = 0; r < 4; ++r) rnr[r] = xxb[r0 + r];

  // phase 1: distances for 4 rows; lane owns 4 consecutive m (coalesced)
#pragma unroll
  for (int chunk = 0; chunk < 2; ++chunk) {
    int m0 = chunk * 1024 + tid * 4;
    const float* ftb = FTb + m0;
    float acc[4][4] = {{0.f}};
    if constexpr ((C & 3) == 0) {
      for (int c = 0; c < C; c += 4) {
        float4 rv[4];
#pragma unroll
        for (int r = 0; r < 4; ++r) rv[r] = *(const float4*)&rowf[r][c];
#pragma unroll
        for (int cc = 0; cc < 4; ++cc) {
          float4 mv = *(const float4*)&ftb[(size_t)(c + cc) * ldft];
#pragma unroll
          for (int r = 0; r < 4; ++r) {
            float rf = ((const float*)&rv[r])[cc];
            acc[r][0] += mv.x * rf;
            acc[r][1] += mv.y * rf;
            acc[r][2] += mv.z * rf;
            acc[r][3] += mv.w * rf;
          }
        }
      }
    } else {
#pragma unroll
      for (int c = 0; c < C; ++c) {
        float4 mv = *(const float4*)&ftb[(size_t)c * ldft];
#pragma unroll
        for (int r = 0; r < 4; ++r) {
          float rf = rowf[r][c];
          acc[r][0] += mv.x * rf;
          acc[r][1] += mv.y * rf;
          acc[r][2] += mv.z * rf;
          acc[r][3] += mv.w * rf;
        }
      }
    }
    float4 xmv = *(const float4*)&xxb[m0];
    const float* xma = (const float*)&xmv;
#pragma unroll
    for (int r = 0; r < 4; ++r) {
      float4 o;
      float* oa = (float*)&o;
#pragma unroll
      for (int j = 0; j < 4; ++j) oa[j] = (2.f * acc[r][j] - rnr[r]) - xma[j];
      *(float4*)&sd[r][m0] = o;
    }
  }
  __syncthreads();

  // phase 2: wave w owns row r0+w; distances live in registers
  int wv = tid >> 6, lane = tid & 63;
  float f[32];
#pragma unroll
  for (int i = 0; i < 32; ++i) f[i] = sd[wv][i * 64 + lane];

  float lv = -FLT_MAX;
  int lm = 0x7fffffff;
#pragma unroll
  for (int i = 0; i < 32; ++i) {
    if (f[i] > lv) { lv = f[i]; lm = i * 64 + lane; }  // ascending i -> min m on ties
  }

  unsigned used = 0u;
  int myidx = 0;
  for (int it = 0; it < KK; ++it) {
    float bv = lv;
    int bm = lm;
#pragma unroll
    for (int off = 32; off > 0; off >>= 1) {
      float ov = __shfl_xor(bv, off);
      int om = __shfl_xor(bm, off);
      if (ov > bv || (ov == bv && om < bm)) { bv = ov; bm = om; }
    }
    if (lane == it) myidx = bm;
    if (lm == bm) {  // exactly the winning lane
      used |= 1u << (lm >> 6);
      lv = -FLT_MAX;
      lm = 0x7fffffff;
#pragma unroll
      for (int i = 0; i < 32; ++i) {
        float v = (used & (1u << i)) ? -FLT_MAX : f[i];
        if (v > lv) { lv = v; lm = i * 64 + lane; }
      }
    }
  }
  if (lane < KK) idx[((size_t)b * NN + r0 + wv) * KK + lane] = myidx;
}

// ---------------------------------------------------------------------------
// prep: split w (O,2C) -> Wa (O,C), Wd = Wb - Wa; sv = g/sqrt(v+eps);
//       tq = (bias - m)*sv + be.  (C==0 -> only sv/tq, for the final layer)
__global__ __launch_bounds__(256) void prep_edge(const float* __restrict__ w,
                                                 const float* __restrict__ bias,
                                                 const float* __restrict__ g,
                                                 const float* __restrict__ be,
                                                 const float* __restrict__ m,
                                                 const float* __restrict__ v,
                                                 float* __restrict__ Wa, float* __restrict__ Wd,
                                                 float* __restrict__ sv, float* __restrict__ tq,
                                                 int O, int C) {
  int i = blockIdx.x * 256 + threadIdx.x;
  if (i < O * C) {
    int o = i / C, c = i % C;
    float wa = w[(size_t)o * 2 * C + c];
    float wb = w[(size_t)o * 2 * C + C + c];
    Wa[i] = wa;
    Wd[i] = wb - wa;
  }
  if (i < O) {
    float s = g[i] / sqrtf(v[i] + EPSV);
    sv[i] = s;
    tq[i] = (bias[i] - m[i]) * s + be[i];
  }
}

// ---------------------------------------------------------------------------
// tiled dual GEMM: P[b][n][o] = (sum_c F[n][c]*Wa[o][c])*sv[o] + (tp?tp[o]:0)
//                  Q[b][n][o] = (sum_c F[n][c]*Wd[o][c])*sv[o] + tq[o]   (DUAL)
template <bool DUAL>
__global__ __launch_bounds__(256) void gemm_pq(const float* __restrict__ F, int ldf, int C,
                                               const float* __restrict__ Wa,
                                               const float* __restrict__ Wd,
                                               const float* __restrict__ sv,
                                               const float* __restrict__ tp,
                                               const float* __restrict__ tq,
                                               float* __restrict__ P, float* __restrict__ Q,
                                               int O) {
  __shared__ __align__(16) float Fs[8][64];
  __shared__ __align__(16) float Was[8][64];
  __shared__ __align__(16) float Wds[8][64];
  int b = blockIdx.z;
  int n0 = blockIdx.x * 64, o0 = blockIdx.y * 64;
  int tid = threadIdx.x;
  int tn = tid & 15, to = tid >> 4;
  float accP[4][4] = {{0.f}};
  float accQ[4][4] = {{0.f}};
  const float* Fb = F + (size_t)b * NN * ldf;

  for (int c0 = 0; c0 < C; c0 += 8) {
    for (int e = tid; e < 512; e += 256) {
      int n = e >> 3, k = e & 7, c = c0 + k;
      Fs[k][n] = (c < C) ? Fb[(size_t)(n0 + n) * ldf + c] : 0.f;
      Was[k][n] = (c < C) ? Wa[(size_t)(o0 + n) * C + c] : 0.f;
      if (DUAL) Wds[k][n] = (c < C) ? Wd[(size_t)(o0 + n) * C + c] : 0.f;
    }
    __syncthreads();
#pragma unroll
    for (int k = 0; k < 8; ++k) {
      float4 fq = *(const float4*)&Fs[k][tn * 4];
      float4 aq = *(const float4*)&Was[k][to * 4];
      float fa[4] = {fq.x, fq.y, fq.z, fq.w};
      float aa[4] = {aq.x, aq.y, aq.z, aq.w};
#pragma unroll
      for (int i = 0; i < 4; ++i)
#pragma unroll
        for (int j = 0; j < 4; ++j) accP[i][j] += fa[i] * aa[j];
      if (DUAL) {
        float4 dq = *(const float4*)&Wds[k][to * 4];
        float da[4] = {dq.x, dq.y, dq.z, dq.w};
#pragma unroll
        for (int i = 0; i < 4; ++i)
#pragma unroll
          for (int j = 0; j < 4; ++j) accQ[i][j] += fa[i] * da[j];
      }
    }
    __syncthreads();
  }

#pragma unroll
  for (int j = 0; j < 4; ++j) {
    int o = o0 + to * 4 + j;
    float s = sv[o];
    float tpv = (tp != nullptr) ? tp[o] : 0.f;
    float tqv = DUAL ? tq[o] : 0.f;
#pragma unroll
    for (int i = 0; i < 4; ++i) {
      int n = n0 + tn * 4 + i;
      size_t base = ((size_t)b * NN + n) * O + o;
      P[base] = accP[i][j] * s + tpv;
      if (DUAL) Q[base] = accQ[i][j] * s + tqv;
    }
  }
}

// ---------------------------------------------------------------------------
// gather-max: out H[b][n][c0+o] = max(0, max_k (P[b][idx[n][k]][o] + Q[b][n][o]))
__global__ void gather_max(const float* __restrict__ P,
                           const float* __restrict__ Q,
                           const int* __restrict__ idx,
                           float* __restrict__ H, int c0, int O) {
  int b = blockIdx.y;
  int n = blockIdx.x;
  int o = threadIdx.x;
  const int* id = idx + ((size_t)b * NN + n) * KK;
  float q = Q[((size_t)b * NN + n) * O + o];
  float best = -FLT_MAX;
#pragma unroll 4
  for (int k = 0; k < KK; ++k) {
    int j = id[k];
    float v = P[((size_t)b * NN + j) * O + o] + q;
    best = fmaxf(best, v);
  }
  best = fmaxf(best, 0.f);  // relu (before max == after max)
  H[((size_t)b * NN + n) * 448 + c0 + o] = best;
}

// ---------------------------------------------------------------------------
// final reduce: out[b][o] = max over n-chunk, via uint atomicMax (values >= 0)
__global__ __launch_bounds__(256) void reduce_max_part(const float* __restrict__ Z,
                                                       unsigned* __restrict__ out) {
  int b = blockIdx.y;
  int o = blockIdx.x * 256 + threadIdx.x;  // o < 512
  int n0 = blockIdx.z * 256;
  float m = 0.f;  // relu floor
  for (int n = n0; n < n0 + 256; ++n) {
    float v = Z[((size_t)b * NN + n) * 512 + o];
    m = fmaxf(m, v);
  }
  // post-relu floats are >= 0 -> uint bit pattern is order-preserving
  atomicMax(&out[(size_t)b * 512 + o], __float_as_uint(m));
}

// ---------------------------------------------------------------------------
extern "C" void kernel_launch(void* const* d_in, const int* in_sizes, int n_in,
                              void* d_out, int out_size, void* d_ws, size_t ws_size,
                              hipStream_t stream) {
  const float* x = (const float*)d_in[0];
  const float* w1 = (const float*)d_in[1];
  const float* b1 = (const float*)d_in[2];
  const float* g1 = (const float*)d_in[3];
  const float* be1 = (const float*)d_in[4];
  const float* m1 = (const float*)d_in[5];
  const float* v1 = (const float*)d_in[6];
  const float* w2 = (const float*)d_in[7];
  const float* b2 = (const float*)d_in[8];
  const float* g2 = (const float*)d_in[9];
  const float* be2 = (const float*)d_in[10];
  const float* m2 = (const float*)d_in[11];
  const float* v2 = (const float*)d_in[12];
  const float* w3 = (const float*)d_in[13];
  const float* b3 = (const float*)d_in[14];
  const float* g3 = (const float*)d_in[15];
  const float* be3 = (const float*)d_in[16];
  const float* m3 = (const float*)d_in[17];
  const float* v3 = (const float*)d_in[18];
  const float* wo = (const float*)d_in[19];
  const float* bo = (const float*)d_in[20];
  const float* go = (const float*)d_in[21];
  const float* beo = (const float*)d_in[22];
  const float* mo = (const float*)d_in[23];
  const float* vo = (const float*)d_in[24];

  char* ws = (char*)d_ws;
  float* H = (float*)(ws + 0);              // 8*2048*448*4 = 29360128
  float* F0 = (float*)(ws + 29360128);      // 196608
  float* xx = (float*)(ws + 29556736);      // 65536
  int* idx = (int*)(ws + 29622272);         // 1310720
  float* P = (float*)(ws + 30932992);       // 16777216
  float* Q = (float*)(ws + 47710208);       // 16777216 (aliased: FT + Z)
  float* Wa = (float*)(ws + 64487424);      // 131072
  float* Wd = (float*)(ws + 64618496);      // 131072
  float* sv = (float*)(ws + 64749568);      // 4096
  float* tq = (float*)(ws + 64753664);      // 4096
  float* Z = P;
  float* FT = Q;  // transposed features; dead Q region outside gemm->gather window

  dim3 blk(256);

  pack_x<<<dim3(8, BB), blk, 0, stream>>>(x, F0, xx);

  // ---- layer 1: C=3, O=64  (x is already [b][c][n] -> serves as FT directly)
  prep_edge<<<dim3(1), blk, 0, stream>>>(w1, b1, g1, be1, m1, v1, Wa, Wd, sv, tq, 64, 3);
  knn3<3><<<dim3(NN / 4, BB), blk, 0, stream>>>(x, NN, F0, 3, xx, idx);
  gemm_pq<true><<<dim3(32, 1, BB), blk, 0, stream>>>(F0, 3, 3, Wa, Wd, sv, nullptr, tq, P, Q, 64);
  gather_max<<<dim3(NN, BB), dim3(64), 0, stream>>>(P, Q, idx, H, 0, 64);
  norms_k<<<dim3(8, BB), blk, 0, stream>>>(H, 448, 64, xx);

  // ---- layer 2: C=64, O=128
  prep_edge<<<dim3(32), blk, 0, stream>>>(w2, b2, g2, be2, m2, v2, Wa, Wd, sv, tq, 128, 64);
  transpose_k<<<dim3(64, 2, BB), blk, 0, stream>>>(H, 448, 64, FT);
  knn3<64><<<dim3(NN / 4, BB), blk, 0, stream>>>(FT, NN, H, 448, xx, idx);
  gemm_pq<true><<<dim3(32, 2, BB), blk, 0, stream>>>(H, 448, 64, Wa, Wd, sv, nullptr, tq, P, Q, 128);
  gather_max<<<dim3(NN, BB), dim3(128), 0, stream>>>(P, Q, idx, H, 64, 128);
  norms_k<<<dim3(8, BB), blk, 0, stream>>>(H + 64, 448, 128, xx);

  // ---- layer 3: C=128, O=256
  prep_edge<<<dim3(128), blk, 0, stream>>>(w3, b3, g3, be3, m3, v3, Wa, Wd, sv, tq, 256, 128);
  transpose_k<<<dim3(64, 4, BB), blk, 0, stream>>>(H + 64, 448, 128, FT);
  knn3<128><<<dim3(NN / 4, BB), blk, 0, stream>>>(FT, NN, H + 64, 448, xx, idx);
  gemm_pq<true><<<dim3(32, 4, BB), blk, 0, stream>>>(H + 64, 448, 128, Wa, Wd, sv, nullptr, tq, P, Q, 256);
  gather_max<<<dim3(NN, BB), dim3(256), 0, stream>>>(P, Q, idx, H, 192, 256);

  // ---- final linear: C=448, O=512 (BN folded via sv/tq-as-tp)
  prep_edge<<<dim3(2), blk, 0, stream>>>(nullptr, bo, go, beo, mo, vo, nullptr, nullptr, sv, tq, 512, 0);
  gemm_pq<false><<<dim3(32, 8, BB), blk, 0, stream>>>(H, 448, 448, wo, nullptr, sv, tq, nullptr, Z, nullptr, 512);

  hipMemsetAsync(d_out, 0, (size_t)out_size * sizeof(float), stream);
  reduce_max_part<<<dim3(2, BB, 8), blk, 0, stream>>>(Z, (unsigned*)d_out);
}

// Round 4
// 959.307 us; speedup vs baseline: 3.5010x; 1.0288x over previous
//
#include <hip/hip_runtime.h>
#include <hip/hip_bf16.h>
#include <cfloat>

// Problem constants
#define BB 8
#define NN 2048
#define KK 20
#define EPSV 1e-5f

// ---------------------------------------------------------------------------
// pack x (B,3,N) -> F0 (B,N,3) and xx (B,N)
__global__ __launch_bounds__(256) void pack_x(const float* __restrict__ x,
                                              float* __restrict__ F0,
                                              float* __restrict__ xx) {
  int b = blockIdx.y;
  int n = blockIdx.x * 256 + threadIdx.x;
  if (n >= NN) return;
  float a = x[((size_t)b * 3 + 0) * NN + n];
  float c = x[((size_t)b * 3 + 1) * NN + n];
  float d = x[((size_t)b * 3 + 2) * NN + n];
  size_t r = (size_t)b * NN + n;
  F0[r * 3 + 0] = a;
  F0[r * 3 + 1] = c;
  F0[r * 3 + 2] = d;
  xx[r] = a * a + c * c + d * d;
}

// ---------------------------------------------------------------------------
// norms over C channels of F (pre-offset pointer), ld = ldf
__global__ __launch_bounds__(256) void norms_k(const float* __restrict__ F, int ldf, int C,
                                               float* __restrict__ xx) {
  int b = blockIdx.y;
  int n = blockIdx.x * 256 + threadIdx.x;
  if (n >= NN) return;
  const float* f = F + ((size_t)b * NN + n) * ldf;
  float s = 0.f;
  for (int c = 0; c < C; c += 4) {
    float4 v = *(const float4*)(f + c);
    s += v.x * v.x + v.y * v.y + v.z * v.z + v.w * v.w;
  }
  xx[(size_t)b * NN + n] = s;
}

// ---------------------------------------------------------------------------
// 32x32 tiled transpose: src [b][n][C] (ld lds_) -> dst [b][c][n] (ld NN)
__global__ __launch_bounds__(256) void transpose_k(const float* __restrict__ src, int lds_, int C,
                                                   float* __restrict__ dst) {
  __shared__ float t[32][33];
  int b = blockIdx.z;
  int n0 = blockIdx.x * 32, c0 = blockIdx.y * 32;
  int tx = threadIdx.x & 31, ty = threadIdx.x >> 5;  // 32 x 8
#pragma unroll
  for (int i = 0; i < 32; i += 8) {
    t[ty + i][tx] = src[((size_t)b * NN + n0 + ty + i) * lds_ + c0 + tx];
  }
  __syncthreads();
#pragma unroll
  for (int i = 0; i < 32; i += 8) {
    dst[((size_t)b * C + c0 + ty + i) * NN + n0 + tx] = t[tx][ty + i];
  }
}

// ---------------------------------------------------------------------------
// kNN v5: 8 rows/block, 512 threads. XCD-swizzled 1D grid: batch = bid&7 so
// each XCD works one batch -> FT (1MB) is L2-resident. Phase 1: lane owns 4
// consecutive m, acc[8][4] in regs (8-row reuse of every FT load); row
// features alias into sd[] head (sd written only after the FMA loop).
// Phase 2: wave w owns row r0+w; 32 dists/lane in regs, 20x wave-argmax.
template <int C>
__global__ __launch_bounds__(512, 4) void knn5(const float* __restrict__ FT,  // [b][C][NN]
                                               const float* __restrict__ F, int ldf,
                                               const float* __restrict__ xx,
                                               int* __restrict__ idx) {
  __shared__ float sd[8 * NN];  // 64KB; sd[0..8*C) doubles as rowf during phase 1
  int b = blockIdx.x & 7;
  int r0 = (blockIdx.x >> 3) * 8;
  int tid = threadIdx.x;
  const float* FTb = FT + (size_t)b * C * NN;
  const float* Fb = F + (size_t)b * NN * ldf;
  const float* xxb = xx + (size_t)b * NN;

  for (int e = tid; e < 8 * C; e += 512) {
    int r = e / C, c = e % C;
    sd[e] = Fb[(size_t)(r0 + r) * ldf + c];  // rowf[r][c] at sd[r*C+c]
  }
  __syncthreads();

  int m0 = tid * 4;
  float acc[8][4];
#pragma unroll
  for (int r = 0; r < 8; ++r)
#pragma unroll
    for (int j = 0; j < 4; ++j) acc[r][j] = 0.f;

  if constexpr ((C & 3) == 0) {
    for (int c = 0; c < C; c += 4) {
      float4 mv[4];
#pragma unroll
      for (int cc = 0; cc < 4; ++cc) mv[cc] = *(const float4*)&FTb[(size_t)(c + cc) * NN + m0];
      float4 rv[8];
#pragma unroll
      for (int r = 0; r < 8; ++r) rv[r] = *(const float4*)&sd[r * C + c];
#pragma unroll
      for (int cc = 0; cc < 4; ++cc) {
#pragma unroll
        for (int r = 0; r < 8; ++r) {
          float rf = ((const float*)&rv[r])[cc];
          acc[r][0] += mv[cc].x * rf;
          acc[r][1] += mv[cc].y * rf;
          acc[r][2] += mv[cc].z * rf;
          acc[r][3] += mv[cc].w * rf;
        }
      }
    }
  } else {
#pragma unroll
    for (int c = 0; c < C; ++c) {
      float4 mv = *(const float4*)&FTb[(size_t)c * NN + m0];
#pragma unroll
      for (int r = 0; r < 8; ++r) {
        float rf = sd[r * C + c];
        acc[r][0] += mv.x * rf;
        acc[r][1] += mv.y * rf;
        acc[r][2] += mv.z * rf;
        acc[r][3] += mv.w * rf;
      }
    }
  }

  float rn[8];
#pragma unroll
  for (int r = 0; r < 8; ++r) rn[r] = xxb[r0 + r];
  float4 xmv = *(const float4*)&xxb[m0];
  const float* xma = (const float*)&xmv;
  __syncthreads();  // all waves done reading rowf region before sd is written

#pragma unroll
  for (int r = 0; r < 8; ++r) {
    float4 o;
    float* oa = (float*)&o;
#pragma unroll
    for (int j = 0; j < 4; ++j) oa[j] = (2.f * acc[r][j] - rn[r]) - xma[j];
    *(float4*)&sd[r * NN + m0] = o;
  }
  __syncthreads();

  // phase 2: wave w owns row r0+w; distances live in registers
  int wv = tid >> 6, lane = tid & 63;
  float f[32];
#pragma unroll
  for (int i = 0; i < 32; ++i) f[i] = sd[wv * NN + i * 64 + lane];

  float lv = -FLT_MAX;
  int lm = 0x7fffffff;
#pragma unroll
  for (int i = 0; i < 32; ++i) {
    if (f[i] > lv) { lv = f[i]; lm = i * 64 + lane; }  // ascending i -> min m on ties
  }

  unsigned used = 0u;
  int myidx = 0;
  for (int it = 0; it < KK; ++it) {
    float bv = lv;
    int bm = lm;
#pragma unroll
    for (int off = 32; off > 0; off >>= 1) {
      float ov = __shfl_xor(bv, off);
      int om = __shfl_xor(bm, off);
      if (ov > bv || (ov == bv && om < bm)) { bv = ov; bm = om; }
    }
    if (lane == it) myidx = bm;
    if (lm == bm) {  // exactly the winning lane
      used |= 1u << (lm >> 6);
      lv = -FLT_MAX;
      lm = 0x7fffffff;
#pragma unroll
      for (int i = 0; i < 32; ++i) {
        float v = (used & (1u << i)) ? -FLT_MAX : f[i];
        if (v > lv) { lv = v; lm = i * 64 + lane; }
      }
    }
  }
  if (lane < KK) idx[((size_t)b * NN + r0 + wv) * KK + lane] = myidx;
}

// ---------------------------------------------------------------------------
// prep: split w (O,2C) -> Wa (O,C), Wd = Wb - Wa; sv = g/sqrt(v+eps);
//       tq = (bias - m)*sv + be.  (C==0 -> only sv/tq, for the final layer)
__global__ __launch_bounds__(256) void prep_edge(const float* __restrict__ w,
                                                 const float* __restrict__ bias,
                                                 const float* __restrict__ g,
                                                 const float* __restrict__ be,
                                                 const float* __restrict__ m,
                                                 const float* __restrict__ v,
                                                 float* __restrict__ Wa, float* __restrict__ Wd,
                                                 float* __restrict__ sv, float* __restrict__ tq,
                                                 int O, int C) {
  int i = blockIdx.x * 256 + threadIdx.x;
  if (i < O * C) {
    int o = i / C, c = i % C;
    float wa = w[(size_t)o * 2 * C + c];
    float wb = w[(size_t)o * 2 * C + C + c];
    Wa[i] = wa;
    Wd[i] = wb - wa;
  }
  if (i < O) {
    float s = g[i] / sqrtf(v[i] + EPSV);
    sv[i] = s;
    tq[i] = (bias[i] - m[i]) * s + be[i];
  }
}

// ---------------------------------------------------------------------------
// tiled dual GEMM: P[b][n][o] = (sum_c F[n][c]*Wa[o][c])*sv[o] + (tp?tp[o]:0)
//                  Q[b][n][o] = (sum_c F[n][c]*Wd[o][c])*sv[o] + tq[o]   (DUAL)
template <bool DUAL>
__global__ __launch_bounds__(256) void gemm_pq(const float* __restrict__ F, int ldf, int C,
                                               const float* __restrict__ Wa,
                                               const float* __restrict__ Wd,
                                               const float* __restrict__ sv,
                                               const float* __restrict__ tp,
                                               const float* __restrict__ tq,
                                               float* __restrict__ P, float* __restrict__ Q,
                                               int O) {
  __shared__ __align__(16) float Fs[8][64];
  __shared__ __align__(16) float Was[8][64];
  __shared__ __align__(16) float Wds[8][64];
  int b = blockIdx.z;
  int n0 = blockIdx.x * 64, o0 = blockIdx.y * 64;
  int tid = threadIdx.x;
  int tn = tid & 15, to = tid >> 4;
  float accP[4][4] = {{0.f}};
  float accQ[4][4] = {{0.f}};
  const float* Fb = F + (size_t)b * NN * ldf;

  for (int c0 = 0; c0 < C; c0 += 8) {
    for (int e = tid; e < 512; e += 256) {
      int n = e >> 3, k = e & 7, c = c0 + k;
      Fs[k][n] = (c < C) ? Fb[(size_t)(n0 + n) * ldf + c] : 0.f;
      Was[k][n] = (c < C) ? Wa[(size_t)(o0 + n) * C + c] : 0.f;
      if (DUAL) Wds[k][n] = (c < C) ? Wd[(size_t)(o0 + n) * C + c] : 0.f;
    }
    __syncthreads();
#pragma unroll
    for (int k = 0; k < 8; ++k) {
      float4 fq = *(const float4*)&Fs[k][tn * 4];
      float4 aq = *(const float4*)&Was[k][to * 4];
      float fa[4] = {fq.x, fq.y, fq.z, fq.w};
      float aa[4] = {aq.x, aq.y, aq.z, aq.w};
#pragma unroll
      for (int i = 0; i < 4; ++i)
#pragma unroll
        for (int j = 0; j < 4; ++j) accP[i][j] += fa[i] * aa[j];
      if (DUAL) {
        float4 dq = *(const float4*)&Wds[k][to * 4];
        float da[4] = {dq.x, dq.y, dq.z, dq.w};
#pragma unroll
        for (int i = 0; i < 4; ++i)
#pragma unroll
          for (int j = 0; j < 4; ++j) accQ[i][j] += fa[i] * da[j];
      }
    }
    __syncthreads();
  }

#pragma unroll
  for (int j = 0; j < 4; ++j) {
    int o = o0 + to * 4 + j;
    float s = sv[o];
    float tpv = (tp != nullptr) ? tp[o] : 0.f;
    float tqv = DUAL ? tq[o] : 0.f;
#pragma unroll
    for (int i = 0; i < 4; ++i) {
      int n = n0 + tn * 4 + i;
      size_t base = ((size_t)b * NN + n) * O + o;
      P[base] = accP[i][j] * s + tpv;
      if (DUAL) Q[base] = accQ[i][j] * s + tqv;
    }
  }
}

// ---------------------------------------------------------------------------
// gather-max: H[b][n][c0+o] = max(0, max_k (P[b][idx[n][k]][o] + Q[b][n][o]))
// 256-thread blocks; 256/O rows n per block.
template <int O>
__global__ __launch_bounds__(256) void gather_max2(const float* __restrict__ P,
                                                   const float* __restrict__ Q,
                                                   const int* __restrict__ idx,
                                                   float* __restrict__ H, int c0) {
  constexpr int NPB = 256 / O;
  int b = blockIdx.y;
  int sub = threadIdx.x / O, o = threadIdx.x % O;
  int n = blockIdx.x * NPB + sub;
  const int* id = idx + ((size_t)b * NN + n) * KK;
  float q = Q[((size_t)b * NN + n) * O + o];
  float best = -FLT_MAX;
#pragma unroll 4
  for (int k = 0; k < KK; ++k) {
    int j = id[k];
    float v = P[((size_t)b * NN + j) * O + o] + q;
    best = fmaxf(best, v);
  }
  best = fmaxf(best, 0.f);  // relu (before max == after max)
  H[((size_t)b * NN + n) * 448 + c0 + o] = best;
}

// ---------------------------------------------------------------------------
// final reduce: out[b][o] = max over n-chunk, via uint atomicMax (values >= 0)
__global__ __launch_bounds__(256) void reduce_max_part(const float* __restrict__ Z,
                                                       unsigned* __restrict__ out) {
  int b = blockIdx.y;
  int o = blockIdx.x * 256 + threadIdx.x;  // o < 512
  int n0 = blockIdx.z * 256;
  float m = 0.f;  // relu floor
  for (int n = n0; n < n0 + 256; ++n) {
    float v = Z[((size_t)b * NN + n) * 512 + o];
    m = fmaxf(m, v);
  }
  // post-relu floats are >= 0 -> uint bit pattern is order-preserving
  atomicMax(&out[(size_t)b * 512 + o], __float_as_uint(m));
}

// ---------------------------------------------------------------------------
extern "C" void kernel_launch(void* const* d_in, const int* in_sizes, int n_in,
                              void* d_out, int out_size, void* d_ws, size_t ws_size,
                              hipStream_t stream) {
  const float* x = (const float*)d_in[0];
  const float* w1 = (const float*)d_in[1];
  const float* b1 = (const float*)d_in[2];
  const float* g1 = (const float*)d_in[3];
  const float* be1 = (const float*)d_in[4];
  const float* m1 = (const float*)d_in[5];
  const float* v1 = (const float*)d_in[6];
  const float* w2 = (const float*)d_in[7];
  const float* b2 = (const float*)d_in[8];
  const float* g2 = (const float*)d_in[9];
  const float* be2 = (const float*)d_in[10];
  const float* m2 = (const float*)d_in[11];
  const float* v2 = (const float*)d_in[12];
  const float* w3 = (const float*)d_in[13];
  const float* b3 = (const float*)d_in[14];
  const float* g3 = (const float*)d_in[15];
  const float* be3 = (const float*)d_in[16];
  const float* m3 = (const float*)d_in[17];
  const float* v3 = (const float*)d_in[18];
  const float* wo = (const float*)d_in[19];
  const float* bo = (const float*)d_in[20];
  const float* go = (const float*)d_in[21];
  const float* beo = (const float*)d_in[22];
  const float* mo = (const float*)d_in[23];
  const float* vo = (const float*)d_in[24];

  char* ws = (char*)d_ws;
  float* H = (float*)(ws + 0);              // 8*2048*448*4 = 29360128
  float* F0 = (float*)(ws + 29360128);      // 196608
  float* xx = (float*)(ws + 29556736);      // 65536
  int* idx = (int*)(ws + 29622272);         // 1310720
  float* P = (float*)(ws + 30932992);       // 16777216
  float* Q = (float*)(ws + 47710208);       // 16777216 (aliased: FT + Z)
  float* Wa = (float*)(ws + 64487424);      // 131072
  float* Wd = (float*)(ws + 64618496);      // 131072
  float* sv = (float*)(ws + 64749568);      // 4096
  float* tq = (float*)(ws + 64753664);      // 4096
  float* Z = P;
  float* FT = Q;  // transposed features; dead Q region outside gemm->gather window

  dim3 blk(256);

  pack_x<<<dim3(8, BB), blk, 0, stream>>>(x, F0, xx);

  // ---- layer 1: C=3, O=64  (x is already [b][c][n] -> serves as FT directly)
  prep_edge<<<dim3(1), blk, 0, stream>>>(w1, b1, g1, be1, m1, v1, Wa, Wd, sv, tq, 64, 3);
  knn5<3><<<dim3(NN), dim3(512), 0, stream>>>(x, F0, 3, xx, idx);
  gemm_pq<true><<<dim3(32, 1, BB), blk, 0, stream>>>(F0, 3, 3, Wa, Wd, sv, nullptr, tq, P, Q, 64);
  gather_max2<64><<<dim3(NN / 4, BB), blk, 0, stream>>>(P, Q, idx, H, 0);
  norms_k<<<dim3(8, BB), blk, 0, stream>>>(H, 448, 64, xx);

  // ---- layer 2: C=64, O=128
  prep_edge<<<dim3(32), blk, 0, stream>>>(w2, b2, g2, be2, m2, v2, Wa, Wd, sv, tq, 128, 64);
  transpose_k<<<dim3(64, 2, BB), blk, 0, stream>>>(H, 448, 64, FT);
  knn5<64><<<dim3(NN), dim3(512), 0, stream>>>(FT, H, 448, xx, idx);
  gemm_pq<true><<<dim3(32, 2, BB), blk, 0, stream>>>(H, 448, 64, Wa, Wd, sv, nullptr, tq, P, Q, 128);
  gather_max2<128><<<dim3(NN / 2, BB), blk, 0, stream>>>(P, Q, idx, H, 64);
  norms_k<<<dim3(8, BB), blk, 0, stream>>>(H + 64, 448, 128, xx);

  // ---- layer 3: C=128, O=256
  prep_edge<<<dim3(128), blk, 0, stream>>>(w3, b3, g3, be3, m3, v3, Wa, Wd, sv, tq, 256, 128);
  transpose_k<<<dim3(64, 4, BB), blk, 0, stream>>>(H + 64, 448, 128, FT);
  knn5<128><<<dim3(NN), dim3(512), 0, stream>>>(FT, H + 64, 448, xx, idx);
  gemm_pq<true><<<dim3(32, 4, BB), blk, 0, stream>>>(H + 64, 448, 128, Wa, Wd, sv, nullptr, tq, P, Q, 256);
  gather_max2<256><<<dim3(NN, BB), blk, 0, stream>>>(P, Q, idx, H, 192);

  // ---- final linear: C=448, O=512 (BN folded via sv/tq-as-tp)
  prep_edge<<<dim3(2), blk, 0, stream>>>(nullptr, bo, go, beo, mo, vo, nullptr, nullptr, sv, tq, 512, 0);
  gemm_pq<false><<<dim3(32, 8, BB), blk, 0, stream>>>(H, 448, 448, wo, nullptr, sv, tq, nullptr, Z, nullptr, 512);

  hipMemsetAsync(d_out, 0, (size_t)out_size * sizeof(float), stream);
  reduce_max_part<<<dim3(2, BB, 8), blk, 0, stream>>>(Z, (unsigned*)d_out);
}